// Round 1
// baseline (1292.063 us; speedup 1.0000x reference)
//
#include <hip/hip_runtime.h>
#include <math.h>

#define N_NODES  50000
#define N_EDGES  800000
#define HIDDEN   128
#define N_LAYERS 3
#define N_MASKED 25000
#define N_GRAPHS 64

// ---------------- degree / norm ----------------
__global__ void count_deg_kernel(const int* __restrict__ dst, unsigned* __restrict__ deg) {
    int i = blockIdx.x * blockDim.x + threadIdx.x;
    if (i < N_EDGES) atomicAdd(&deg[dst[i]], 1u);
}

// in-place: buffer holds u32 counts, becomes float dinv
__global__ void dinv_kernel(float* __restrict__ buf) {
    int i = blockIdx.x * blockDim.x + threadIdx.x;
    if (i < N_NODES) {
        unsigned d = ((const unsigned*)buf)[i];
        buf[i] = rsqrtf((float)(d + 1u));   // +1 for self-loop
    }
}

// ---------------- GEMM: Out[r][c] = sum_k A[r][k] * W[k][c], 128x128 W ----------------
__global__ __launch_bounds__(256, 2) void gemm128_kernel(const float* __restrict__ A,
                                                         const float* __restrict__ W,
                                                         float* __restrict__ Out,
                                                         int nrows) {
    __shared__ float Wl[128 * 128];   // 64 KB
    __shared__ float Rb[32 * 128];    // 16 KB
    const int tid = threadIdx.x;

    for (int i = tid * 4; i < 128 * 128; i += 256 * 4)
        *(float4*)&Wl[i] = *(const float4*)&W[i];
    __syncthreads();

    const int c4 = (tid & 31) * 4;   // output col group (4 cols)
    const int rr = tid >> 5;         // row slot 0..7

    for (int rowBase = blockIdx.x * 32; rowBase < nrows; rowBase += gridDim.x * 32) {
        // stage 32 rows
        for (int i = tid * 4; i < 32 * 128; i += 256 * 4) {
            int r = i >> 7;
            int row = rowBase + r;
            float4 v = make_float4(0.f, 0.f, 0.f, 0.f);
            if (row < nrows) v = *(const float4*)&A[row * 128 + (i & 127)];
            *(float4*)&Rb[i] = v;
        }
        __syncthreads();

        float4 acc0 = make_float4(0,0,0,0), acc1 = make_float4(0,0,0,0);
        float4 acc2 = make_float4(0,0,0,0), acc3 = make_float4(0,0,0,0);
        #pragma unroll 4
        for (int k = 0; k < 128; ++k) {
            float4 w = *(const float4*)&Wl[k * 128 + c4];
            float h0 = Rb[(rr +  0) * 128 + k];
            float h1 = Rb[(rr +  8) * 128 + k];
            float h2 = Rb[(rr + 16) * 128 + k];
            float h3 = Rb[(rr + 24) * 128 + k];
            acc0.x += h0 * w.x; acc0.y += h0 * w.y; acc0.z += h0 * w.z; acc0.w += h0 * w.w;
            acc1.x += h1 * w.x; acc1.y += h1 * w.y; acc1.z += h1 * w.z; acc1.w += h1 * w.w;
            acc2.x += h2 * w.x; acc2.y += h2 * w.y; acc2.z += h2 * w.z; acc2.w += h2 * w.w;
            acc3.x += h3 * w.x; acc3.y += h3 * w.y; acc3.z += h3 * w.z; acc3.w += h3 * w.w;
        }

        int r0 = rowBase + rr;
        if (r0      < nrows) *(float4*)&Out[(r0     ) * 128 + c4] = acc0;
        if (r0 + 8  < nrows) *(float4*)&Out[(r0 +  8) * 128 + c4] = acc1;
        if (r0 + 16 < nrows) *(float4*)&Out[(r0 + 16) * 128 + c4] = acc2;
        if (r0 + 24 < nrows) *(float4*)&Out[(r0 + 24) * 128 + c4] = acc3;
        __syncthreads();
    }
}

// ---------------- self-loop init: h[v] = hw[v] * dinv[v]^2 ----------------
__global__ void selfloop_kernel(const float* __restrict__ hw, const float* __restrict__ dinv,
                                float* __restrict__ h) {
    int idx = blockIdx.x * blockDim.x + threadIdx.x;
    if (idx < N_NODES * HIDDEN) {
        float di = dinv[idx >> 7];
        h[idx] = hw[idx] * di * di;
    }
}

// ---------------- edge scatter: h[dst] += hw[src] * dinv[src]*dinv[dst] ----------------
__global__ void scatter_kernel(const int* __restrict__ src, const int* __restrict__ dst,
                               const float* __restrict__ hw, const float* __restrict__ dinv,
                               float* __restrict__ h) {
    const int total = N_EDGES * HIDDEN;  // 102.4M
    for (int idx = blockIdx.x * blockDim.x + threadIdx.x; idx < total;
         idx += gridDim.x * blockDim.x) {
        int e = idx >> 7;
        int f = idx & 127;
        int s = src[e];
        int d = dst[e];
        float nrm = dinv[s] * dinv[d];
        unsafeAtomicAdd(&h[d * 128 + f], hw[s * 128 + f] * nrm);
    }
}

// ---------------- bias + ELU (in place) ----------------
__global__ void bias_elu_kernel(float* __restrict__ h, const float* __restrict__ b) {
    int idx = blockIdx.x * blockDim.x + threadIdx.x;
    if (idx < N_NODES * HIDDEN) {
        float x = h[idx] + b[idx & 127];
        h[idx] = x > 0.f ? x : expf(x) - 1.f;
    }
}

// ---------------- masked segment-max pool + dot ----------------
__device__ __forceinline__ int lower_bound_i(const int* __restrict__ a, int n, int key) {
    int lo = 0, hi = n;
    while (lo < hi) {
        int mid = (lo + hi) >> 1;
        if (a[mid] < key) lo = mid + 1; else hi = mid;
    }
    return lo;
}

__global__ void pool_dot_kernel(const float* __restrict__ h, const int* __restrict__ mask,
                                const int* __restrict__ batch, const float* __restrict__ w,
                                const float* __restrict__ b, float* __restrict__ out) {
    const int g = blockIdx.x;   // graph id, 64 blocks
    const int f = threadIdx.x;  // feature, 128 threads

    int s = lower_bound_i(batch, N_MASKED, g);
    int e = lower_bound_i(batch, N_MASKED, g + 1);

    float m = -INFINITY;
    for (int i = s; i < e; ++i) {
        int node = mask[i];
        m = fmaxf(m, h[node * 128 + f]);
    }
    float val = m * w[f];
    #pragma unroll
    for (int off = 32; off > 0; off >>= 1) val += __shfl_down(val, off);

    __shared__ float ps[2];
    if ((threadIdx.x & 63) == 0) ps[threadIdx.x >> 6] = val;
    __syncthreads();
    if (threadIdx.x == 0) out[g] = ps[0] + ps[1] + b[0];
}

extern "C" void kernel_launch(void* const* d_in, const int* in_sizes, int n_in,
                              void* d_out, int out_size, void* d_ws, size_t ws_size,
                              hipStream_t stream) {
    const float* x      = (const float*)d_in[0];
    const int*   ei     = (const int*)d_in[1];          // [2][E] int32
    const int*   mask   = (const int*)d_in[2];
    const int*   batch  = (const int*)d_in[3];
    const float* conv_w = (const float*)d_in[4];        // [3][128][128]
    const float* conv_b = (const float*)d_in[5];        // [3][128]
    const float* lt1_w  = (const float*)d_in[6];        // [128]
    const float* lt1_b  = (const float*)d_in[7];        // [1]
    float* out = (float*)d_out;

    const int* e_src = ei;
    const int* e_dst = ei + N_EDGES;

    char* ws = (char*)d_ws;
    float* dinv = (float*)ws;                               // 50000 f32 (first u32 deg)
    float* hw   = (float*)(ws + ((N_NODES * 4 + 255) & ~255));
    float* hbuf = hw + (size_t)N_NODES * HIDDEN;

    // degrees -> dinv
    hipMemsetAsync(dinv, 0, N_NODES * sizeof(unsigned), stream);
    count_deg_kernel<<<(N_EDGES + 255) / 256, 256, 0, stream>>>(e_dst, (unsigned*)dinv);
    dinv_kernel<<<(N_NODES + 255) / 256, 256, 0, stream>>>(dinv);

    const int NH = N_NODES * HIDDEN;
    const float* h_in = x;
    for (int l = 0; l < N_LAYERS; ++l) {
        gemm128_kernel<<<512, 256, 0, stream>>>(h_in, conv_w + l * 128 * 128, hw, N_NODES);
        selfloop_kernel<<<(NH + 255) / 256, 256, 0, stream>>>(hw, dinv, hbuf);
        scatter_kernel<<<32768, 256, 0, stream>>>(e_src, e_dst, hw, dinv, hbuf);
        bias_elu_kernel<<<(NH + 255) / 256, 256, 0, stream>>>(hbuf, conv_b + l * HIDDEN);
        h_in = hbuf;
    }

    pool_dot_kernel<<<N_GRAPHS, HIDDEN, 0, stream>>>(hbuf, mask, batch, lt1_w, lt1_b, out);
}

// Round 2
// 458.927 us; speedup vs baseline: 2.8154x; 2.8154x over previous
//
#include <hip/hip_runtime.h>
#include <math.h>

#define N_NODES  50000
#define N_EDGES  800000
#define HIDDEN   128
#define N_LAYERS 3
#define N_MASKED 25000
#define N_GRAPHS 64

// ---------------- degree count (in-degree via dst) ----------------
__global__ void count_deg_kernel(const int* __restrict__ dst, unsigned* __restrict__ deg) {
    int i = blockIdx.x * blockDim.x + threadIdx.x;
    if (i < N_EDGES) atomicAdd(&deg[dst[i]], 1u);
}

__global__ void dinv_kernel(const unsigned* __restrict__ deg, float* __restrict__ dinv) {
    int i = blockIdx.x * blockDim.x + threadIdx.x;
    if (i < N_NODES) dinv[i] = rsqrtf((float)(deg[i] + 1u));   // +1 self-loop
}

// ---------------- prefix sum: per-block inclusive scan ----------------
__global__ void scan_block_kernel(const unsigned* __restrict__ deg, unsigned* __restrict__ incl,
                                  unsigned* __restrict__ bsum) {
    __shared__ unsigned s[1024];
    int i = blockIdx.x * 1024 + threadIdx.x;
    unsigned v = (i < N_NODES) ? deg[i] : 0u;
    s[threadIdx.x] = v;
    __syncthreads();
    for (int off = 1; off < 1024; off <<= 1) {
        unsigned t = (threadIdx.x >= off) ? s[threadIdx.x - off] : 0u;
        __syncthreads();
        s[threadIdx.x] += t;
        __syncthreads();
    }
    if (i < N_NODES) incl[i] = s[threadIdx.x];
    if (threadIdx.x == 1023) bsum[blockIdx.x] = s[1023];
}

__global__ void scan_bsum_kernel(unsigned* __restrict__ bsum, int n) {
    if (blockIdx.x == 0 && threadIdx.x == 0) {
        unsigned run = 0;
        for (int i = 0; i < n; ++i) { unsigned t = bsum[i]; bsum[i] = run; run += t; }
    }
}

__global__ void scan_finalize_kernel(const unsigned* __restrict__ incl,
                                     const unsigned* __restrict__ bsum_ex,
                                     unsigned* __restrict__ row_ptr,
                                     unsigned* __restrict__ cursor) {
    int i = blockIdx.x * blockDim.x + threadIdx.x;
    if (i <= N_NODES) {
        unsigned v = (i == 0) ? 0u : incl[i - 1] + bsum_ex[(i - 1) >> 10];
        row_ptr[i] = v;
        if (i < N_NODES) cursor[i] = v;
    }
}

// ---------------- CSR fill ----------------
__global__ void fill_csr_kernel(const int* __restrict__ src, const int* __restrict__ dst,
                                unsigned* __restrict__ cursor, int* __restrict__ csr_src) {
    int e = blockIdx.x * blockDim.x + threadIdx.x;
    if (e < N_EDGES) {
        unsigned p = atomicAdd(&cursor[dst[e]], 1u);
        csr_src[p] = src[e];
    }
}

// ---------------- GEMM: Out[r][c] = sum_k A[r][k] * W[k][c], 128x128 W ----------------
__global__ __launch_bounds__(256, 2) void gemm128_kernel(const float* __restrict__ A,
                                                         const float* __restrict__ W,
                                                         float* __restrict__ Out,
                                                         int nrows) {
    __shared__ float Wl[128 * 128];   // 64 KB
    __shared__ float Rb[32 * 128];    // 16 KB
    const int tid = threadIdx.x;

    for (int i = tid * 4; i < 128 * 128; i += 256 * 4)
        *(float4*)&Wl[i] = *(const float4*)&W[i];
    __syncthreads();

    const int c4 = (tid & 31) * 4;
    const int rr = tid >> 5;

    for (int rowBase = blockIdx.x * 32; rowBase < nrows; rowBase += gridDim.x * 32) {
        for (int i = tid * 4; i < 32 * 128; i += 256 * 4) {
            int r = i >> 7;
            int row = rowBase + r;
            float4 v = make_float4(0.f, 0.f, 0.f, 0.f);
            if (row < nrows) v = *(const float4*)&A[row * 128 + (i & 127)];
            *(float4*)&Rb[i] = v;
        }
        __syncthreads();

        float4 acc0 = make_float4(0,0,0,0), acc1 = make_float4(0,0,0,0);
        float4 acc2 = make_float4(0,0,0,0), acc3 = make_float4(0,0,0,0);
        #pragma unroll 4
        for (int k = 0; k < 128; ++k) {
            float4 w = *(const float4*)&Wl[k * 128 + c4];
            float h0 = Rb[(rr +  0) * 128 + k];
            float h1 = Rb[(rr +  8) * 128 + k];
            float h2 = Rb[(rr + 16) * 128 + k];
            float h3 = Rb[(rr + 24) * 128 + k];
            acc0.x += h0 * w.x; acc0.y += h0 * w.y; acc0.z += h0 * w.z; acc0.w += h0 * w.w;
            acc1.x += h1 * w.x; acc1.y += h1 * w.y; acc1.z += h1 * w.z; acc1.w += h1 * w.w;
            acc2.x += h2 * w.x; acc2.y += h2 * w.y; acc2.z += h2 * w.z; acc2.w += h2 * w.w;
            acc3.x += h3 * w.x; acc3.y += h3 * w.y; acc3.z += h3 * w.z; acc3.w += h3 * w.w;
        }

        int r0 = rowBase + rr;
        if (r0      < nrows) *(float4*)&Out[(r0     ) * 128 + c4] = acc0;
        if (r0 + 8  < nrows) *(float4*)&Out[(r0 +  8) * 128 + c4] = acc1;
        if (r0 + 16 < nrows) *(float4*)&Out[(r0 + 16) * 128 + c4] = acc2;
        if (r0 + 24 < nrows) *(float4*)&Out[(r0 + 24) * 128 + c4] = acc3;
        __syncthreads();
    }
}

// ---------------- CSR gather + self-loop + bias + ELU ----------------
// one wave per item; item -> node v (identity or via nodes[]); out row = item index
__global__ __launch_bounds__(256) void gather_kernel(const float* __restrict__ hw,
                                                     const unsigned* __restrict__ row_ptr,
                                                     const int* __restrict__ csr_src,
                                                     const float* __restrict__ dinv,
                                                     const float* __restrict__ bias,
                                                     float* __restrict__ out,
                                                     const int* __restrict__ nodes,
                                                     int n_items) {
    int w = (blockIdx.x * blockDim.x + threadIdx.x) >> 6;
    if (w >= n_items) return;
    const int lane = threadIdx.x & 63;
    const int v = nodes ? nodes[w] : w;

    const unsigned s0 = row_ptr[v], e0 = row_ptr[v + 1];
    const float2* __restrict__ hw2 = (const float2*)hw;

    float ax = 0.f, ay = 0.f;
    unsigned i = s0;
    for (; i + 2 <= e0; i += 2) {
        int sA = csr_src[i];
        int sB = csr_src[i + 1];
        float wA = dinv[sA];
        float wB = dinv[sB];
        float2 tA = hw2[(size_t)sA * 64 + lane];
        float2 tB = hw2[(size_t)sB * 64 + lane];
        ax += wA * tA.x + wB * tB.x;
        ay += wA * tA.y + wB * tB.y;
    }
    if (i < e0) {
        int sA = csr_src[i];
        float wA = dinv[sA];
        float2 tA = hw2[(size_t)sA * 64 + lane];
        ax += wA * tA.x;
        ay += wA * tA.y;
    }

    float dv = dinv[v];
    float2 self = hw2[(size_t)v * 64 + lane];
    float ox = dv * ax + dv * dv * self.x + bias[lane * 2];
    float oy = dv * ay + dv * dv * self.y + bias[lane * 2 + 1];
    ox = ox > 0.f ? ox : expm1f(ox);
    oy = oy > 0.f ? oy : expm1f(oy);
    ((float2*)out)[(size_t)w * 64 + lane] = make_float2(ox, oy);
}

// ---------------- masked segment-max pool + dot (xm is compact [M,128]) ----------------
__device__ __forceinline__ int lower_bound_i(const int* __restrict__ a, int n, int key) {
    int lo = 0, hi = n;
    while (lo < hi) {
        int mid = (lo + hi) >> 1;
        if (a[mid] < key) lo = mid + 1; else hi = mid;
    }
    return lo;
}

__global__ void pool_dot_kernel(const float* __restrict__ xm, const int* __restrict__ batch,
                                const float* __restrict__ w, const float* __restrict__ b,
                                float* __restrict__ out) {
    const int g = blockIdx.x;
    const int f = threadIdx.x;

    int s = lower_bound_i(batch, N_MASKED, g);
    int e = lower_bound_i(batch, N_MASKED, g + 1);

    float m = -INFINITY;
    for (int i = s; i < e; ++i) m = fmaxf(m, xm[(size_t)i * 128 + f]);

    float val = m * w[f];
    #pragma unroll
    for (int off = 32; off > 0; off >>= 1) val += __shfl_down(val, off);

    __shared__ float ps[2];
    if ((threadIdx.x & 63) == 0) ps[threadIdx.x >> 6] = val;
    __syncthreads();
    if (threadIdx.x == 0) out[g] = ps[0] + ps[1] + b[0];
}

extern "C" void kernel_launch(void* const* d_in, const int* in_sizes, int n_in,
                              void* d_out, int out_size, void* d_ws, size_t ws_size,
                              hipStream_t stream) {
    const float* x      = (const float*)d_in[0];
    const int*   ei     = (const int*)d_in[1];
    const int*   mask   = (const int*)d_in[2];
    const int*   batch  = (const int*)d_in[3];
    const float* conv_w = (const float*)d_in[4];
    const float* conv_b = (const float*)d_in[5];
    const float* lt1_w  = (const float*)d_in[6];
    const float* lt1_b  = (const float*)d_in[7];
    float* out = (float*)d_out;

    const int* e_src = ei;
    const int* e_dst = ei + N_EDGES;

    // ---- workspace carve-up (aligned to 256B) ----
    char* ws = (char*)d_ws;
    auto carve = [&](size_t bytes) { char* p = ws; ws += (bytes + 255) & ~(size_t)255; return p; };
    unsigned* deg     = (unsigned*)carve(N_NODES * 4);
    float*    dinv    = (float*)   carve(N_NODES * 4);
    unsigned* row_ptr = (unsigned*)carve((N_NODES + 1) * 4);
    unsigned* cursor  = (unsigned*)carve(N_NODES * 4);
    unsigned* bsum    = (unsigned*)carve(64 * 4);
    int*      csr_src = (int*)     carve((size_t)N_EDGES * 4);
    float*    hw      = (float*)   carve((size_t)N_NODES * HIDDEN * 4);
    float*    hbuf    = (float*)   carve((size_t)N_NODES * HIDDEN * 4);
    unsigned* incl    = (unsigned*)csr_src;  // alias: dead before fill_csr runs
    float*    xm      = hbuf;                // alias: layer-2 h dead after layer-3 GEMM

    const int NB_SCAN = (N_NODES + 1023) / 1024;  // 49

    // ---- build dinv + CSR (per call; atomic fill order only perturbs fp sum order ~1e-6) ----
    hipMemsetAsync(deg, 0, N_NODES * sizeof(unsigned), stream);
    count_deg_kernel<<<(N_EDGES + 255) / 256, 256, 0, stream>>>(e_dst, deg);
    dinv_kernel<<<(N_NODES + 255) / 256, 256, 0, stream>>>(deg, dinv);
    scan_block_kernel<<<NB_SCAN, 1024, 0, stream>>>(deg, incl, bsum);
    scan_bsum_kernel<<<1, 64, 0, stream>>>(bsum, NB_SCAN);
    scan_finalize_kernel<<<(N_NODES + 256) / 256, 256, 0, stream>>>(incl, bsum, row_ptr, cursor);
    fill_csr_kernel<<<(N_EDGES + 255) / 256, 256, 0, stream>>>(e_src, e_dst, cursor, csr_src);

    // ---- 3 GCN layers ----
    const float* h_in = x;
    for (int l = 0; l < N_LAYERS; ++l) {
        gemm128_kernel<<<512, 256, 0, stream>>>(h_in, conv_w + l * 128 * 128, hw, N_NODES);
        if (l < N_LAYERS - 1) {
            gather_kernel<<<(N_NODES * 64 + 255) / 256, 256, 0, stream>>>(
                hw, row_ptr, csr_src, dinv, conv_b + l * HIDDEN, hbuf, nullptr, N_NODES);
            h_in = hbuf;
        } else {
            // last layer: only masked nodes are consumed downstream
            gather_kernel<<<(N_MASKED * 64 + 255) / 256, 256, 0, stream>>>(
                hw, row_ptr, csr_src, dinv, conv_b + l * HIDDEN, xm, mask, N_MASKED);
        }
    }

    pool_dot_kernel<<<N_GRAPHS, HIDDEN, 0, stream>>>(xm, batch, lt1_w, lt1_b, out);
}

// Round 3
// 435.037 us; speedup vs baseline: 2.9700x; 1.0549x over previous
//
#include <hip/hip_runtime.h>
#include <math.h>

#define N_NODES  50000
#define N_EDGES  800000
#define HIDDEN   128
#define N_LAYERS 3
#define N_MASKED 25000
#define N_GRAPHS 64

// ordered float<->uint mapping (monotonic): preserves IEEE total order
__device__ __forceinline__ unsigned fmap(float f) {
    unsigned u = __float_as_uint(f);
    return (u & 0x80000000u) ? ~u : (u | 0x80000000u);
}
__device__ __forceinline__ float funmap(unsigned u) {
    return __uint_as_float((u & 0x80000000u) ? (u & 0x7FFFFFFFu) : ~u);
}

// ---------------- degree count (in-degree via dst) ----------------
__global__ void count_deg_kernel(const int* __restrict__ dst, unsigned* __restrict__ deg) {
    int i = blockIdx.x * blockDim.x + threadIdx.x;
    if (i < N_EDGES) atomicAdd(&deg[dst[i]], 1u);
}

__global__ void dinv_kernel(const unsigned* __restrict__ deg, float* __restrict__ dinv) {
    int i = blockIdx.x * blockDim.x + threadIdx.x;
    if (i < N_NODES) dinv[i] = rsqrtf((float)(deg[i] + 1u));   // +1 self-loop
}

// ---------------- prefix sum: per-block inclusive scan ----------------
__global__ void scan_block_kernel(const unsigned* __restrict__ deg, unsigned* __restrict__ incl,
                                  unsigned* __restrict__ bsum) {
    __shared__ unsigned s[1024];
    int i = blockIdx.x * 1024 + threadIdx.x;
    unsigned v = (i < N_NODES) ? deg[i] : 0u;
    s[threadIdx.x] = v;
    __syncthreads();
    for (int off = 1; off < 1024; off <<= 1) {
        unsigned t = (threadIdx.x >= off) ? s[threadIdx.x - off] : 0u;
        __syncthreads();
        s[threadIdx.x] += t;
        __syncthreads();
    }
    if (i < N_NODES) incl[i] = s[threadIdx.x];
    if (threadIdx.x == 1023) bsum[blockIdx.x] = s[1023];
}

__global__ void scan_bsum_kernel(unsigned* __restrict__ bsum, int n) {
    if (blockIdx.x == 0 && threadIdx.x == 0) {
        unsigned run = 0;
        for (int i = 0; i < n; ++i) { unsigned t = bsum[i]; bsum[i] = run; run += t; }
    }
}

__global__ void scan_finalize_kernel(const unsigned* __restrict__ incl,
                                     const unsigned* __restrict__ bsum_ex,
                                     unsigned* __restrict__ row_ptr,
                                     unsigned* __restrict__ cursor) {
    int i = blockIdx.x * blockDim.x + threadIdx.x;
    if (i <= N_NODES) {
        unsigned v = (i == 0) ? 0u : incl[i - 1] + bsum_ex[(i - 1) >> 10];
        row_ptr[i] = v;
        if (i < N_NODES) cursor[i] = v;
    }
}

// ---------------- CSR fill ----------------
__global__ void fill_csr_kernel(const int* __restrict__ src, const int* __restrict__ dst,
                                unsigned* __restrict__ cursor, int* __restrict__ csr_src) {
    int e = blockIdx.x * blockDim.x + threadIdx.x;
    if (e < N_EDGES) {
        unsigned p = atomicAdd(&cursor[dst[e]], 1u);
        csr_src[p] = src[e];
    }
}

// ---------------- GEMM: Out[r][c] = sum_k A[r][k] * W[k][c], 128x128 W ----------------
__global__ __launch_bounds__(256, 2) void gemm128_kernel(const float* __restrict__ A,
                                                         const float* __restrict__ W,
                                                         float* __restrict__ Out,
                                                         int nrows) {
    __shared__ float Wl[128 * 128];   // 64 KB
    __shared__ float Rb[32 * 128];    // 16 KB
    const int tid = threadIdx.x;

    for (int i = tid * 4; i < 128 * 128; i += 256 * 4)
        *(float4*)&Wl[i] = *(const float4*)&W[i];
    __syncthreads();

    const int c4 = (tid & 31) * 4;
    const int rr = tid >> 5;

    for (int rowBase = blockIdx.x * 32; rowBase < nrows; rowBase += gridDim.x * 32) {
        for (int i = tid * 4; i < 32 * 128; i += 256 * 4) {
            int r = i >> 7;
            int row = rowBase + r;
            float4 v = make_float4(0.f, 0.f, 0.f, 0.f);
            if (row < nrows) v = *(const float4*)&A[row * 128 + (i & 127)];
            *(float4*)&Rb[i] = v;
        }
        __syncthreads();

        float4 acc0 = make_float4(0,0,0,0), acc1 = make_float4(0,0,0,0);
        float4 acc2 = make_float4(0,0,0,0), acc3 = make_float4(0,0,0,0);
        #pragma unroll 4
        for (int k = 0; k < 128; ++k) {
            float4 w = *(const float4*)&Wl[k * 128 + c4];
            float h0 = Rb[(rr +  0) * 128 + k];
            float h1 = Rb[(rr +  8) * 128 + k];
            float h2 = Rb[(rr + 16) * 128 + k];
            float h3 = Rb[(rr + 24) * 128 + k];
            acc0.x += h0 * w.x; acc0.y += h0 * w.y; acc0.z += h0 * w.z; acc0.w += h0 * w.w;
            acc1.x += h1 * w.x; acc1.y += h1 * w.y; acc1.z += h1 * w.z; acc1.w += h1 * w.w;
            acc2.x += h2 * w.x; acc2.y += h2 * w.y; acc2.z += h2 * w.z; acc2.w += h2 * w.w;
            acc3.x += h3 * w.x; acc3.y += h3 * w.y; acc3.z += h3 * w.z; acc3.w += h3 * w.w;
        }

        int r0 = rowBase + rr;
        if (r0      < nrows) *(float4*)&Out[(r0     ) * 128 + c4] = acc0;
        if (r0 + 8  < nrows) *(float4*)&Out[(r0 +  8) * 128 + c4] = acc1;
        if (r0 + 16 < nrows) *(float4*)&Out[(r0 + 16) * 128 + c4] = acc2;
        if (r0 + 24 < nrows) *(float4*)&Out[(r0 + 24) * 128 + c4] = acc3;
        __syncthreads();
    }
}

// ---------------- CSR gather + self-loop + bias + ELU ----------------
// one wave per item. If gmax==nullptr: write full row to out[w].
// Else (last layer): node v = nodes[w], graph g = batch[w]; atomicMax mapped
// ELU outputs into gmax[g*128+f] — fuses global_max_pool, no xm materialized.
__global__ __launch_bounds__(256) void gather_kernel(const float* __restrict__ hw,
                                                     const unsigned* __restrict__ row_ptr,
                                                     const int* __restrict__ csr_src,
                                                     const float* __restrict__ dinv,
                                                     const float* __restrict__ bias,
                                                     float* __restrict__ out,
                                                     const int* __restrict__ nodes,
                                                     const int* __restrict__ batch,
                                                     unsigned* __restrict__ gmax,
                                                     int n_items) {
    int w = (blockIdx.x * blockDim.x + threadIdx.x) >> 6;
    if (w >= n_items) return;
    const int lane = threadIdx.x & 63;
    const int v = nodes ? nodes[w] : w;

    const unsigned s0 = row_ptr[v], e0 = row_ptr[v + 1];
    const float2* __restrict__ hw2 = (const float2*)hw;

    float ax = 0.f, ay = 0.f;
    unsigned i = s0;
    for (; i + 2 <= e0; i += 2) {
        int sA = csr_src[i];
        int sB = csr_src[i + 1];
        float wA = dinv[sA];
        float wB = dinv[sB];
        float2 tA = hw2[(size_t)sA * 64 + lane];
        float2 tB = hw2[(size_t)sB * 64 + lane];
        ax += wA * tA.x + wB * tB.x;
        ay += wA * tA.y + wB * tB.y;
    }
    if (i < e0) {
        int sA = csr_src[i];
        float wA = dinv[sA];
        float2 tA = hw2[(size_t)sA * 64 + lane];
        ax += wA * tA.x;
        ay += wA * tA.y;
    }

    float dv = dinv[v];
    float2 self = hw2[(size_t)v * 64 + lane];
    float ox = dv * ax + dv * dv * self.x + bias[lane * 2];
    float oy = dv * ay + dv * dv * self.y + bias[lane * 2 + 1];
    ox = ox > 0.f ? ox : expm1f(ox);
    oy = oy > 0.f ? oy : expm1f(oy);

    if (gmax) {
        int g = batch[w];
        atomicMax(&gmax[g * 128 + lane * 2],     fmap(ox));
        atomicMax(&gmax[g * 128 + lane * 2 + 1], fmap(oy));
    } else {
        ((float2*)out)[(size_t)w * 64 + lane] = make_float2(ox, oy);
    }
}

// ---------------- init gmax to mapped(-inf) ----------------
__global__ void gmax_init_kernel(unsigned* __restrict__ gmax) {
    int i = blockIdx.x * blockDim.x + threadIdx.x;
    if (i < N_GRAPHS * 128) gmax[i] = 0x007FFFFFu;  // fmap(-inf)
}

// ---------------- finish: out[g] = sum_f unmap(gmax[g][f]) * w[f] + b ----------------
__global__ void pool_finish_kernel(const unsigned* __restrict__ gmax,
                                   const float* __restrict__ w, const float* __restrict__ b,
                                   float* __restrict__ out) {
    const int g = blockIdx.x;
    const int f = threadIdx.x;
    float val = funmap(gmax[g * 128 + f]) * w[f];
    #pragma unroll
    for (int off = 32; off > 0; off >>= 1) val += __shfl_down(val, off);
    __shared__ float ps[2];
    if ((threadIdx.x & 63) == 0) ps[threadIdx.x >> 6] = val;
    __syncthreads();
    if (threadIdx.x == 0) out[g] = ps[0] + ps[1] + b[0];
}

extern "C" void kernel_launch(void* const* d_in, const int* in_sizes, int n_in,
                              void* d_out, int out_size, void* d_ws, size_t ws_size,
                              hipStream_t stream) {
    const float* x      = (const float*)d_in[0];
    const int*   ei     = (const int*)d_in[1];
    const int*   mask   = (const int*)d_in[2];
    const int*   batch  = (const int*)d_in[3];
    const float* conv_w = (const float*)d_in[4];
    const float* conv_b = (const float*)d_in[5];
    const float* lt1_w  = (const float*)d_in[6];
    const float* lt1_b  = (const float*)d_in[7];
    float* out = (float*)d_out;

    const int* e_src = ei;
    const int* e_dst = ei + N_EDGES;

    // ---- workspace carve-up (aligned to 256B) ----
    char* ws = (char*)d_ws;
    auto carve = [&](size_t bytes) { char* p = ws; ws += (bytes + 255) & ~(size_t)255; return p; };
    unsigned* deg     = (unsigned*)carve(N_NODES * 4);
    float*    dinv    = (float*)   carve(N_NODES * 4);
    unsigned* row_ptr = (unsigned*)carve((N_NODES + 1) * 4);
    unsigned* cursor  = (unsigned*)carve(N_NODES * 4);
    unsigned* bsum    = (unsigned*)carve(64 * 4);
    unsigned* gmax    = (unsigned*)carve(N_GRAPHS * 128 * 4);
    int*      csr_src = (int*)     carve((size_t)N_EDGES * 4);
    float*    hw      = (float*)   carve((size_t)N_NODES * HIDDEN * 4);
    float*    hbuf    = (float*)   carve((size_t)N_NODES * HIDDEN * 4);
    unsigned* incl    = (unsigned*)csr_src;  // alias: dead before fill_csr runs

    const int NB_SCAN = (N_NODES + 1023) / 1024;  // 49

    // ---- build dinv + CSR ----
    hipMemsetAsync(deg, 0, N_NODES * sizeof(unsigned), stream);
    count_deg_kernel<<<(N_EDGES + 255) / 256, 256, 0, stream>>>(e_dst, deg);
    dinv_kernel<<<(N_NODES + 255) / 256, 256, 0, stream>>>(deg, dinv);
    scan_block_kernel<<<NB_SCAN, 1024, 0, stream>>>(deg, incl, bsum);
    scan_bsum_kernel<<<1, 64, 0, stream>>>(bsum, NB_SCAN);
    scan_finalize_kernel<<<(N_NODES + 256) / 256, 256, 0, stream>>>(incl, bsum, row_ptr, cursor);
    fill_csr_kernel<<<(N_EDGES + 255) / 256, 256, 0, stream>>>(e_src, e_dst, cursor, csr_src);
    gmax_init_kernel<<<(N_GRAPHS * 128 + 255) / 256, 256, 0, stream>>>(gmax);

    // ---- 3 GCN layers ----
    const float* h_in = x;
    for (int l = 0; l < N_LAYERS; ++l) {
        gemm128_kernel<<<512, 256, 0, stream>>>(h_in, conv_w + l * 128 * 128, hw, N_NODES);
        if (l < N_LAYERS - 1) {
            gather_kernel<<<(N_NODES * 64 + 255) / 256, 256, 0, stream>>>(
                hw, row_ptr, csr_src, dinv, conv_b + l * HIDDEN, hbuf,
                nullptr, nullptr, nullptr, N_NODES);
            h_in = hbuf;
        } else {
            gather_kernel<<<(N_MASKED * 64 + 255) / 256, 256, 0, stream>>>(
                hw, row_ptr, csr_src, dinv, conv_b + l * HIDDEN, nullptr,
                mask, batch, gmax, N_MASKED);
        }
    }

    pool_finish_kernel<<<N_GRAPHS, HIDDEN, 0, stream>>>(gmax, lt1_w, lt1_b, out);
}

// Round 4
// 409.259 us; speedup vs baseline: 3.1571x; 1.0630x over previous
//
#include <hip/hip_runtime.h>
#include <math.h>

#define N_NODES  50000
#define N_EDGES  800000
#define HIDDEN   128
#define N_LAYERS 3
#define N_MASKED 25000
#define N_GRAPHS 64

// ordered float<->uint mapping (monotonic): preserves IEEE total order
__device__ __forceinline__ unsigned fmap(float f) {
    unsigned u = __float_as_uint(f);
    return (u & 0x80000000u) ? ~u : (u | 0x80000000u);
}
__device__ __forceinline__ float funmap(unsigned u) {
    return __uint_as_float((u & 0x80000000u) ? (u & 0x7FFFFFFFu) : ~u);
}

// ---------------- degree count (in-degree via dst) ----------------
__global__ void count_deg_kernel(const int* __restrict__ dst, unsigned* __restrict__ deg) {
    int i = blockIdx.x * blockDim.x + threadIdx.x;
    if (i < N_EDGES) atomicAdd(&deg[dst[i]], 1u);
}

__global__ void dinv_kernel(const unsigned* __restrict__ deg, float* __restrict__ dinv) {
    int i = blockIdx.x * blockDim.x + threadIdx.x;
    if (i < N_NODES) dinv[i] = rsqrtf((float)(deg[i] + 1u));   // +1 self-loop
}

// ---------------- prefix sum: per-block inclusive scan ----------------
__global__ void scan_block_kernel(const unsigned* __restrict__ deg, unsigned* __restrict__ incl,
                                  unsigned* __restrict__ bsum) {
    __shared__ unsigned s[1024];
    int i = blockIdx.x * 1024 + threadIdx.x;
    unsigned v = (i < N_NODES) ? deg[i] : 0u;
    s[threadIdx.x] = v;
    __syncthreads();
    for (int off = 1; off < 1024; off <<= 1) {
        unsigned t = (threadIdx.x >= off) ? s[threadIdx.x - off] : 0u;
        __syncthreads();
        s[threadIdx.x] += t;
        __syncthreads();
    }
    if (i < N_NODES) incl[i] = s[threadIdx.x];
    if (threadIdx.x == 1023) bsum[blockIdx.x] = s[1023];
}

__global__ void scan_bsum_kernel(unsigned* __restrict__ bsum, int n) {
    if (blockIdx.x == 0 && threadIdx.x == 0) {
        unsigned run = 0;
        for (int i = 0; i < n; ++i) { unsigned t = bsum[i]; bsum[i] = run; run += t; }
    }
}

__global__ void scan_finalize_kernel(const unsigned* __restrict__ incl,
                                     const unsigned* __restrict__ bsum_ex,
                                     unsigned* __restrict__ row_ptr,
                                     unsigned* __restrict__ cursor) {
    int i = blockIdx.x * blockDim.x + threadIdx.x;
    if (i <= N_NODES) {
        unsigned v = (i == 0) ? 0u : incl[i - 1] + bsum_ex[(i - 1) >> 10];
        row_ptr[i] = v;
        if (i < N_NODES) cursor[i] = v;
    }
}

// ---------------- CSR fill ----------------
__global__ void fill_csr_kernel(const int* __restrict__ src, const int* __restrict__ dst,
                                unsigned* __restrict__ cursor, int* __restrict__ csr_src) {
    int e = blockIdx.x * blockDim.x + threadIdx.x;
    if (e < N_EDGES) {
        unsigned p = atomicAdd(&cursor[dst[e]], 1u);
        csr_src[p] = src[e];
    }
}

// ---------------- GEMM + row-scale: Out[r][:] = dinv[r] * (A[r][:] @ W) ----------------
__global__ __launch_bounds__(256, 2) void gemm128_kernel(const float* __restrict__ A,
                                                         const float* __restrict__ W,
                                                         const float* __restrict__ dinv,
                                                         float* __restrict__ Out,
                                                         int nrows) {
    __shared__ float Wl[128 * 128];   // 64 KB
    __shared__ float Rb[32 * 128];    // 16 KB
    const int tid = threadIdx.x;

    for (int i = tid * 4; i < 128 * 128; i += 256 * 4)
        *(float4*)&Wl[i] = *(const float4*)&W[i];
    __syncthreads();

    const int c4 = (tid & 31) * 4;
    const int rr = tid >> 5;

    for (int rowBase = blockIdx.x * 32; rowBase < nrows; rowBase += gridDim.x * 32) {
        for (int i = tid * 4; i < 32 * 128; i += 256 * 4) {
            int r = i >> 7;
            int row = rowBase + r;
            float4 v = make_float4(0.f, 0.f, 0.f, 0.f);
            if (row < nrows) v = *(const float4*)&A[row * 128 + (i & 127)];
            *(float4*)&Rb[i] = v;
        }
        __syncthreads();

        float4 acc0 = make_float4(0,0,0,0), acc1 = make_float4(0,0,0,0);
        float4 acc2 = make_float4(0,0,0,0), acc3 = make_float4(0,0,0,0);
        #pragma unroll 4
        for (int k = 0; k < 128; ++k) {
            float4 w = *(const float4*)&Wl[k * 128 + c4];
            float h0 = Rb[(rr +  0) * 128 + k];
            float h1 = Rb[(rr +  8) * 128 + k];
            float h2 = Rb[(rr + 16) * 128 + k];
            float h3 = Rb[(rr + 24) * 128 + k];
            acc0.x += h0 * w.x; acc0.y += h0 * w.y; acc0.z += h0 * w.z; acc0.w += h0 * w.w;
            acc1.x += h1 * w.x; acc1.y += h1 * w.y; acc1.z += h1 * w.z; acc1.w += h1 * w.w;
            acc2.x += h2 * w.x; acc2.y += h2 * w.y; acc2.z += h2 * w.z; acc2.w += h2 * w.w;
            acc3.x += h3 * w.x; acc3.y += h3 * w.y; acc3.z += h3 * w.z; acc3.w += h3 * w.w;
        }

        int r0 = rowBase + rr;
        if (r0 < nrows) {
            float d = dinv[r0];
            acc0.x *= d; acc0.y *= d; acc0.z *= d; acc0.w *= d;
            *(float4*)&Out[(size_t)r0 * 128 + c4] = acc0;
        }
        if (r0 + 8 < nrows) {
            float d = dinv[r0 + 8];
            acc1.x *= d; acc1.y *= d; acc1.z *= d; acc1.w *= d;
            *(float4*)&Out[(size_t)(r0 + 8) * 128 + c4] = acc1;
        }
        if (r0 + 16 < nrows) {
            float d = dinv[r0 + 16];
            acc2.x *= d; acc2.y *= d; acc2.z *= d; acc2.w *= d;
            *(float4*)&Out[(size_t)(r0 + 16) * 128 + c4] = acc2;
        }
        if (r0 + 24 < nrows) {
            float d = dinv[r0 + 24];
            acc3.x *= d; acc3.y *= d; acc3.z *= d; acc3.w *= d;
            *(float4*)&Out[(size_t)(r0 + 24) * 128 + c4] = acc3;
        }
        __syncthreads();
    }
}

// ---------------- CSR gather over pre-scaled rows ----------------
// wave wid -> (item w = wid>>1, half = wid&1); lane covers one feature.
// o = dinv[v] * (hws[v][f] + sum_{s in N(v)} hws[s][f]) + bias[f]; ELU.
// gmax==nullptr: write out[w][f]. Else node v=nodes[w], g=batch[w]: atomicMax fmap(o).
__global__ __launch_bounds__(256) void gather_kernel(const float* __restrict__ hws,
                                                     const unsigned* __restrict__ row_ptr,
                                                     const int* __restrict__ csr_src,
                                                     const float* __restrict__ dinv,
                                                     const float* __restrict__ bias,
                                                     float* __restrict__ out,
                                                     const int* __restrict__ nodes,
                                                     const int* __restrict__ batch,
                                                     unsigned* __restrict__ gmax,
                                                     int n_items) {
    int wid = (blockIdx.x * blockDim.x + threadIdx.x) >> 6;
    int w = wid >> 1;
    if (w >= n_items) return;
    const int f = ((wid & 1) << 6) | (threadIdx.x & 63);
    const int v = nodes ? nodes[w] : w;

    const unsigned s0 = row_ptr[v], e0 = row_ptr[v + 1];
    const float* __restrict__ base = hws + f;

    float a0 = base[(size_t)v << 7];   // self-loop row
    float a1 = 0.f, a2 = 0.f, a3 = 0.f;

    unsigned i = s0;
    int sA = 0, sB = 0, sC = 0, sD = 0;
    if (i + 4 <= e0) { sA = csr_src[i]; sB = csr_src[i+1]; sC = csr_src[i+2]; sD = csr_src[i+3]; }
    for (; i + 8 <= e0; i += 4) {
        int nA = csr_src[i+4], nB = csr_src[i+5], nC = csr_src[i+6], nD = csr_src[i+7];
        a0 += base[(size_t)sA << 7];
        a1 += base[(size_t)sB << 7];
        a2 += base[(size_t)sC << 7];
        a3 += base[(size_t)sD << 7];
        sA = nA; sB = nB; sC = nC; sD = nD;
    }
    if (i + 4 <= e0) {
        a0 += base[(size_t)sA << 7];
        a1 += base[(size_t)sB << 7];
        a2 += base[(size_t)sC << 7];
        a3 += base[(size_t)sD << 7];
        i += 4;
    }
    for (; i < e0; ++i) a0 += base[(size_t)csr_src[i] << 7];

    float o = dinv[v] * ((a0 + a1) + (a2 + a3)) + bias[f];
    o = o > 0.f ? o : expm1f(o);

    if (gmax) {
        atomicMax(&gmax[batch[w] * 128 + f], fmap(o));
    } else {
        out[((size_t)w << 7) + f] = o;
    }
}

// ---------------- init gmax to mapped(-inf) ----------------
__global__ void gmax_init_kernel(unsigned* __restrict__ gmax) {
    int i = blockIdx.x * blockDim.x + threadIdx.x;
    if (i < N_GRAPHS * 128) gmax[i] = 0x007FFFFFu;  // fmap(-inf)
}

// ---------------- finish: out[g] = sum_f unmap(gmax[g][f]) * w[f] + b ----------------
__global__ void pool_finish_kernel(const unsigned* __restrict__ gmax,
                                   const float* __restrict__ w, const float* __restrict__ b,
                                   float* __restrict__ out) {
    const int g = blockIdx.x;
    const int f = threadIdx.x;
    float val = funmap(gmax[g * 128 + f]) * w[f];
    #pragma unroll
    for (int off = 32; off > 0; off >>= 1) val += __shfl_down(val, off);
    __shared__ float ps[2];
    if ((threadIdx.x & 63) == 0) ps[threadIdx.x >> 6] = val;
    __syncthreads();
    if (threadIdx.x == 0) out[g] = ps[0] + ps[1] + b[0];
}

extern "C" void kernel_launch(void* const* d_in, const int* in_sizes, int n_in,
                              void* d_out, int out_size, void* d_ws, size_t ws_size,
                              hipStream_t stream) {
    const float* x      = (const float*)d_in[0];
    const int*   ei     = (const int*)d_in[1];
    const int*   mask   = (const int*)d_in[2];
    const int*   batch  = (const int*)d_in[3];
    const float* conv_w = (const float*)d_in[4];
    const float* conv_b = (const float*)d_in[5];
    const float* lt1_w  = (const float*)d_in[6];
    const float* lt1_b  = (const float*)d_in[7];
    float* out = (float*)d_out;

    const int* e_src = ei;
    const int* e_dst = ei + N_EDGES;

    // ---- workspace carve-up (aligned to 256B) ----
    char* ws = (char*)d_ws;
    auto carve = [&](size_t bytes) { char* p = ws; ws += (bytes + 255) & ~(size_t)255; return p; };
    unsigned* deg     = (unsigned*)carve(N_NODES * 4);
    float*    dinv    = (float*)   carve(N_NODES * 4);
    unsigned* row_ptr = (unsigned*)carve((N_NODES + 1) * 4);
    unsigned* cursor  = (unsigned*)carve(N_NODES * 4);
    unsigned* bsum    = (unsigned*)carve(64 * 4);
    unsigned* gmax    = (unsigned*)carve(N_GRAPHS * 128 * 4);
    int*      csr_src = (int*)     carve((size_t)N_EDGES * 4);
    float*    hws     = (float*)   carve((size_t)N_NODES * HIDDEN * 4);
    float*    hbuf    = (float*)   carve((size_t)N_NODES * HIDDEN * 4);
    unsigned* incl    = (unsigned*)csr_src;  // alias: dead before fill_csr runs

    const int NB_SCAN = (N_NODES + 1023) / 1024;  // 49

    // ---- build dinv + CSR ----
    hipMemsetAsync(deg, 0, N_NODES * sizeof(unsigned), stream);
    count_deg_kernel<<<(N_EDGES + 255) / 256, 256, 0, stream>>>(e_dst, deg);
    dinv_kernel<<<(N_NODES + 255) / 256, 256, 0, stream>>>(deg, dinv);
    scan_block_kernel<<<NB_SCAN, 1024, 0, stream>>>(deg, incl, bsum);
    scan_bsum_kernel<<<1, 64, 0, stream>>>(bsum, NB_SCAN);
    scan_finalize_kernel<<<(N_NODES + 256) / 256, 256, 0, stream>>>(incl, bsum, row_ptr, cursor);
    fill_csr_kernel<<<(N_EDGES + 255) / 256, 256, 0, stream>>>(e_src, e_dst, cursor, csr_src);
    gmax_init_kernel<<<(N_GRAPHS * 128 + 255) / 256, 256, 0, stream>>>(gmax);

    // ---- 3 GCN layers ----
    const float* h_in = x;
    for (int l = 0; l < N_LAYERS; ++l) {
        gemm128_kernel<<<512, 256, 0, stream>>>(h_in, conv_w + l * 128 * 128, dinv, hws, N_NODES);
        if (l < N_LAYERS - 1) {
            // waves = 2 * N_NODES (one per half-row)
            gather_kernel<<<(N_NODES * 2 * 64 + 255) / 256, 256, 0, stream>>>(
                hws, row_ptr, csr_src, dinv, conv_b + l * HIDDEN, hbuf,
                nullptr, nullptr, nullptr, N_NODES);
            h_in = hbuf;
        } else {
            gather_kernel<<<(N_MASKED * 2 * 64 + 255) / 256, 256, 0, stream>>>(
                hws, row_ptr, csr_src, dinv, conv_b + l * HIDDEN, nullptr,
                mask, batch, gmax, N_MASKED);
        }
    }

    pool_finish_kernel<<<N_GRAPHS, HIDDEN, 0, stream>>>(gmax, lt1_w, lt1_b, out);
}

// Round 5
// 404.960 us; speedup vs baseline: 3.1906x; 1.0106x over previous
//
#include <hip/hip_runtime.h>
#include <math.h>

#define N_NODES  50000
#define N_EDGES  800000
#define HIDDEN   128
#define N_LAYERS 3
#define N_MASKED 25000
#define N_GRAPHS 64

// ordered float<->uint mapping (monotonic): preserves IEEE total order
__device__ __forceinline__ unsigned fmap(float f) {
    unsigned u = __float_as_uint(f);
    return (u & 0x80000000u) ? ~u : (u | 0x80000000u);
}
__device__ __forceinline__ float funmap(unsigned u) {
    return __uint_as_float((u & 0x80000000u) ? (u & 0x7FFFFFFFu) : ~u);
}

// ---------------- degree count (in-degree via dst) ----------------
__global__ void count_deg_kernel(const int* __restrict__ dst, unsigned* __restrict__ deg) {
    int i = blockIdx.x * blockDim.x + threadIdx.x;
    if (i < N_EDGES) atomicAdd(&deg[dst[i]], 1u);
}

__global__ void dinv_kernel(const unsigned* __restrict__ deg, float* __restrict__ dinv) {
    int i = blockIdx.x * blockDim.x + threadIdx.x;
    if (i < N_NODES) dinv[i] = rsqrtf((float)(deg[i] + 1u));   // +1 self-loop
}

// ---------------- prefix sum: per-block inclusive scan ----------------
__global__ void scan_block_kernel(const unsigned* __restrict__ deg, unsigned* __restrict__ incl,
                                  unsigned* __restrict__ bsum) {
    __shared__ unsigned s[1024];
    int i = blockIdx.x * 1024 + threadIdx.x;
    unsigned v = (i < N_NODES) ? deg[i] : 0u;
    s[threadIdx.x] = v;
    __syncthreads();
    for (int off = 1; off < 1024; off <<= 1) {
        unsigned t = (threadIdx.x >= off) ? s[threadIdx.x - off] : 0u;
        __syncthreads();
        s[threadIdx.x] += t;
        __syncthreads();
    }
    if (i < N_NODES) incl[i] = s[threadIdx.x];
    if (threadIdx.x == 1023) bsum[blockIdx.x] = s[1023];
}

__global__ void scan_bsum_kernel(unsigned* __restrict__ bsum, int n) {
    if (blockIdx.x == 0 && threadIdx.x == 0) {
        unsigned run = 0;
        for (int i = 0; i < n; ++i) { unsigned t = bsum[i]; bsum[i] = run; run += t; }
    }
}

__global__ void scan_finalize_kernel(const unsigned* __restrict__ incl,
                                     const unsigned* __restrict__ bsum_ex,
                                     unsigned* __restrict__ row_ptr,
                                     unsigned* __restrict__ cursor) {
    int i = blockIdx.x * blockDim.x + threadIdx.x;
    if (i <= N_NODES) {
        unsigned v = (i == 0) ? 0u : incl[i - 1] + bsum_ex[(i - 1) >> 10];
        row_ptr[i] = v;
        if (i < N_NODES) cursor[i] = v;
    }
}

// ---------------- CSR fill ----------------
__global__ void fill_csr_kernel(const int* __restrict__ src, const int* __restrict__ dst,
                                unsigned* __restrict__ cursor, int* __restrict__ csr_src) {
    int e = blockIdx.x * blockDim.x + threadIdx.x;
    if (e < N_EDGES) {
        unsigned p = atomicAdd(&cursor[dst[e]], 1u);
        csr_src[p] = src[e];
    }
}

// ---------------- GEMM + row-scale: Out[r][:] = dinv[r] * (A[r][:] @ W) ----------------
__global__ __launch_bounds__(256, 2) void gemm128_kernel(const float* __restrict__ A,
                                                         const float* __restrict__ W,
                                                         const float* __restrict__ dinv,
                                                         float* __restrict__ Out,
                                                         int nrows) {
    __shared__ float Wl[128 * 128];   // 64 KB
    __shared__ float Rb[32 * 128];    // 16 KB
    const int tid = threadIdx.x;

    for (int i = tid * 4; i < 128 * 128; i += 256 * 4)
        *(float4*)&Wl[i] = *(const float4*)&W[i];
    __syncthreads();

    const int c4 = (tid & 31) * 4;
    const int rr = tid >> 5;

    for (int rowBase = blockIdx.x * 32; rowBase < nrows; rowBase += gridDim.x * 32) {
        for (int i = tid * 4; i < 32 * 128; i += 256 * 4) {
            int row = rowBase + (i >> 7);
            float4 v = make_float4(0.f, 0.f, 0.f, 0.f);
            if (row < nrows) v = *(const float4*)&A[(size_t)row * 128 + (i & 127)];
            *(float4*)&Rb[i] = v;
        }
        __syncthreads();

        float4 acc[4];
        #pragma unroll
        for (int m = 0; m < 4; ++m) acc[m] = make_float4(0, 0, 0, 0);

        // k in blocks of 4: all LDS traffic via ds_read_b128
        #pragma unroll 4
        for (int k4 = 0; k4 < 128; k4 += 4) {
            float h0[4], h1[4], h2[4], h3[4];
            *(float4*)h0 = *(const float4*)&Rb[(rr +  0) * 128 + k4];
            *(float4*)h1 = *(const float4*)&Rb[(rr +  8) * 128 + k4];
            *(float4*)h2 = *(const float4*)&Rb[(rr + 16) * 128 + k4];
            *(float4*)h3 = *(const float4*)&Rb[(rr + 24) * 128 + k4];
            #pragma unroll
            for (int j = 0; j < 4; ++j) {
                float4 wv = *(const float4*)&Wl[(k4 + j) * 128 + c4];
                acc[0].x += h0[j] * wv.x; acc[0].y += h0[j] * wv.y;
                acc[0].z += h0[j] * wv.z; acc[0].w += h0[j] * wv.w;
                acc[1].x += h1[j] * wv.x; acc[1].y += h1[j] * wv.y;
                acc[1].z += h1[j] * wv.z; acc[1].w += h1[j] * wv.w;
                acc[2].x += h2[j] * wv.x; acc[2].y += h2[j] * wv.y;
                acc[2].z += h2[j] * wv.z; acc[2].w += h2[j] * wv.w;
                acc[3].x += h3[j] * wv.x; acc[3].y += h3[j] * wv.y;
                acc[3].z += h3[j] * wv.z; acc[3].w += h3[j] * wv.w;
            }
        }

        #pragma unroll
        for (int m = 0; m < 4; ++m) {
            int r0 = rowBase + rr + m * 8;
            if (r0 < nrows) {
                float d = dinv[r0];
                float4 o = acc[m];
                o.x *= d; o.y *= d; o.z *= d; o.w *= d;
                *(float4*)&Out[(size_t)r0 * 128 + c4] = o;
            }
        }
        __syncthreads();
    }
}

// ---------------- CSR gather over pre-scaled rows ----------------
// wave wid -> (item w = wid>>1, half = wid&1); lane covers one feature.
// o = dinv[v] * (hws[v][f] + sum_{s in N(v)} hws[s][f]) + bias[f]; ELU.
// gmax==nullptr: write out[w][f]. Else node v=nodes[w], g=batch[w]: atomicMax fmap(o).
__global__ __launch_bounds__(256) void gather_kernel(const float* __restrict__ hws,
                                                     const unsigned* __restrict__ row_ptr,
                                                     const int* __restrict__ csr_src,
                                                     const float* __restrict__ dinv,
                                                     const float* __restrict__ bias,
                                                     float* __restrict__ out,
                                                     const int* __restrict__ nodes,
                                                     const int* __restrict__ batch,
                                                     unsigned* __restrict__ gmax,
                                                     int n_items) {
    int wid = (blockIdx.x * blockDim.x + threadIdx.x) >> 6;
    int w = wid >> 1;
    if (w >= n_items) return;
    const int f = ((wid & 1) << 6) | (threadIdx.x & 63);
    const int v = nodes ? nodes[w] : w;

    const unsigned s0 = row_ptr[v], e0 = row_ptr[v + 1];
    const float* __restrict__ base = hws + f;

    float acc[8];
    #pragma unroll
    for (int j = 0; j < 8; ++j) acc[j] = 0.f;
    acc[0] = base[(size_t)v << 7];   // self-loop row

    unsigned i = s0;
    if (i + 8 <= e0) {
        int idx[8];
        #pragma unroll
        for (int j = 0; j < 8; ++j) idx[j] = csr_src[i + j];
        for (; i + 16 <= e0; i += 8) {
            int nxt[8];
            #pragma unroll
            for (int j = 0; j < 8; ++j) nxt[j] = csr_src[i + 8 + j];
            #pragma unroll
            for (int j = 0; j < 8; ++j) acc[j] += base[(size_t)idx[j] << 7];
            #pragma unroll
            for (int j = 0; j < 8; ++j) idx[j] = nxt[j];
        }
        #pragma unroll
        for (int j = 0; j < 8; ++j) acc[j] += base[(size_t)idx[j] << 7];
        i += 8;
    }
    if (i + 4 <= e0) {
        #pragma unroll
        for (int j = 0; j < 4; ++j) acc[j] += base[(size_t)csr_src[i + j] << 7];
        i += 4;
    }
    for (; i < e0; ++i) acc[0] += base[(size_t)csr_src[i] << 7];

    float o = dinv[v] * (((acc[0] + acc[1]) + (acc[2] + acc[3])) +
                         ((acc[4] + acc[5]) + (acc[6] + acc[7]))) + bias[f];
    o = o > 0.f ? o : expm1f(o);

    if (gmax) {
        atomicMax(&gmax[batch[w] * 128 + f], fmap(o));
    } else {
        out[((size_t)w << 7) + f] = o;
    }
}

// ---------------- init gmax to mapped(-inf) ----------------
__global__ void gmax_init_kernel(unsigned* __restrict__ gmax) {
    int i = blockIdx.x * blockDim.x + threadIdx.x;
    if (i < N_GRAPHS * 128) gmax[i] = 0x007FFFFFu;  // fmap(-inf)
}

// ---------------- finish: out[g] = sum_f unmap(gmax[g][f]) * w[f] + b ----------------
__global__ void pool_finish_kernel(const unsigned* __restrict__ gmax,
                                   const float* __restrict__ w, const float* __restrict__ b,
                                   float* __restrict__ out) {
    const int g = blockIdx.x;
    const int f = threadIdx.x;
    float val = funmap(gmax[g * 128 + f]) * w[f];
    #pragma unroll
    for (int off = 32; off > 0; off >>= 1) val += __shfl_down(val, off);
    __shared__ float ps[2];
    if ((threadIdx.x & 63) == 0) ps[threadIdx.x >> 6] = val;
    __syncthreads();
    if (threadIdx.x == 0) out[g] = ps[0] + ps[1] + b[0];
}

extern "C" void kernel_launch(void* const* d_in, const int* in_sizes, int n_in,
                              void* d_out, int out_size, void* d_ws, size_t ws_size,
                              hipStream_t stream) {
    const float* x      = (const float*)d_in[0];
    const int*   ei     = (const int*)d_in[1];
    const int*   mask   = (const int*)d_in[2];
    const int*   batch  = (const int*)d_in[3];
    const float* conv_w = (const float*)d_in[4];
    const float* conv_b = (const float*)d_in[5];
    const float* lt1_w  = (const float*)d_in[6];
    const float* lt1_b  = (const float*)d_in[7];
    float* out = (float*)d_out;

    const int* e_src = ei;
    const int* e_dst = ei + N_EDGES;

    // ---- workspace carve-up (aligned to 256B) ----
    char* ws = (char*)d_ws;
    auto carve = [&](size_t bytes) { char* p = ws; ws += (bytes + 255) & ~(size_t)255; return p; };
    unsigned* deg     = (unsigned*)carve(N_NODES * 4);
    float*    dinv    = (float*)   carve(N_NODES * 4);
    unsigned* row_ptr = (unsigned*)carve((N_NODES + 1) * 4);
    unsigned* cursor  = (unsigned*)carve(N_NODES * 4);
    unsigned* bsum    = (unsigned*)carve(64 * 4);
    unsigned* gmax    = (unsigned*)carve(N_GRAPHS * 128 * 4);
    int*      csr_src = (int*)     carve((size_t)N_EDGES * 4);
    float*    hws     = (float*)   carve((size_t)N_NODES * HIDDEN * 4);
    float*    hbuf    = (float*)   carve((size_t)N_NODES * HIDDEN * 4);
    unsigned* incl    = (unsigned*)csr_src;  // alias: dead before fill_csr runs

    const int NB_SCAN = (N_NODES + 1023) / 1024;  // 49

    // ---- build dinv + CSR ----
    hipMemsetAsync(deg, 0, N_NODES * sizeof(unsigned), stream);
    count_deg_kernel<<<(N_EDGES + 255) / 256, 256, 0, stream>>>(e_dst, deg);
    dinv_kernel<<<(N_NODES + 255) / 256, 256, 0, stream>>>(deg, dinv);
    scan_block_kernel<<<NB_SCAN, 1024, 0, stream>>>(deg, incl, bsum);
    scan_bsum_kernel<<<1, 64, 0, stream>>>(bsum, NB_SCAN);
    scan_finalize_kernel<<<(N_NODES + 256) / 256, 256, 0, stream>>>(incl, bsum, row_ptr, cursor);
    fill_csr_kernel<<<(N_EDGES + 255) / 256, 256, 0, stream>>>(e_src, e_dst, cursor, csr_src);
    gmax_init_kernel<<<(N_GRAPHS * 128 + 255) / 256, 256, 0, stream>>>(gmax);

    // ---- 3 GCN layers ----
    const float* h_in = x;
    for (int l = 0; l < N_LAYERS; ++l) {
        gemm128_kernel<<<512, 256, 0, stream>>>(h_in, conv_w + l * 128 * 128, dinv, hws, N_NODES);
        if (l < N_LAYERS - 1) {
            gather_kernel<<<(N_NODES * 2 * 64 + 255) / 256, 256, 0, stream>>>(
                hws, row_ptr, csr_src, dinv, conv_b + l * HIDDEN, hbuf,
                nullptr, nullptr, nullptr, N_NODES);
            h_in = hbuf;
        } else {
            gather_kernel<<<(N_MASKED * 2 * 64 + 255) / 256, 256, 0, stream>>>(
                hws, row_ptr, csr_src, dinv, conv_b + l * HIDDEN, nullptr,
                mask, batch, gmax, N_MASKED);
        }
    }

    pool_finish_kernel<<<N_GRAPHS, HIDDEN, 0, stream>>>(gmax, lt1_w, lt1_b, out);
}